// Round 9
// baseline (130.465 us; speedup 1.0000x reference)
//
#include <hip/hip_runtime.h>

// Problem constants
#define D_MODEL 1024
#define NHEAD   16
#define DK      64
#define BATCH   2
#define SEQ     2048
#define M_TOT   (BATCH*SEQ)   // 4096

typedef unsigned short u16;
typedef unsigned int   u32;
typedef __attribute__((ext_vector_type(8))) __bf16 bf16x8;
typedef __attribute__((ext_vector_type(8))) u16   u16x8;
typedef __attribute__((ext_vector_type(4))) u16   u16x4;
typedef __attribute__((ext_vector_type(4))) float f32x4;

typedef const __attribute__((address_space(1))) u32* gas_ptr;
typedef __attribute__((address_space(3))) u32*       las_ptr;

__device__ __forceinline__ void gload16(const u16* g, u16* l) {
  __builtin_amdgcn_global_load_lds((gas_ptr)g, (las_ptr)l, 16, 0, 0);
}

__device__ __forceinline__ u16 bfc(float f) {
  union { __bf16 h; u16 u; } v; v.h = (__bf16)f; return v.u;
}

#define BAR() do { \
  __builtin_amdgcn_sched_barrier(0); \
  __builtin_amdgcn_s_barrier(); \
  __builtin_amdgcn_sched_barrier(0); \
} while (0)

// ---------------- fused fp32 -> bf16 convert (x + 4 weights, 1 launch) ----------------
__global__ void cvt_all(const float* __restrict__ x,
                        const float* __restrict__ wq, const float* __restrict__ wk,
                        const float* __restrict__ wv, const float* __restrict__ wo,
                        u16* __restrict__ xbf, u16* __restrict__ wbf) {
  const int y = blockIdx.y;
  const float* src;
  u16* dst;
  int n8;
  if (y == 0)      { src = x;  dst = xbf;                n8 = M_TOT * D_MODEL / 8; }
  else if (y == 1) { src = wq; dst = wbf;                n8 = 1024 * 1024 / 8; }
  else if (y == 2) { src = wk; dst = wbf + 1 * 1048576;  n8 = 1024 * 1024 / 8; }
  else if (y == 3) { src = wv; dst = wbf + 2 * 1048576;  n8 = 1024 * 1024 / 8; }
  else             { src = wo; dst = wbf + 3 * 1048576;  n8 = 1024 * 1024 / 8; }
  for (int i = blockIdx.x * blockDim.x + threadIdx.x; i < n8; i += gridDim.x * blockDim.x) {
    const float4* s = (const float4*)src + (size_t)i * 2;
    float4 a = s[0], b = s[1];
    u16x8 o;
    o[0]=bfc(a.x); o[1]=bfc(a.y); o[2]=bfc(a.z); o[3]=bfc(a.w);
    o[4]=bfc(b.x); o[5]=bfc(b.y); o[6]=bfc(b.z); o[7]=bfc(b.w);
    *((u16x8*)dst + i) = o;
  }
}

// Q scale: 1/sqrt(64) * log2(e)  (attention works in exp2 domain)
#define QSCALE 0.18033688011112042f

// ---------------- fused QKV projection: 64x64 tiles, 128-thr blocks (10/CU) ----------------
// 3072 blocks; 16 KB LDS -> 10 resident blocks/CU (20 waves) for latency hiding.
// Proven chunk swizzle: chunk' = chunk ^ ((row>>1)&3)  (0 bank conflicts, r7).
__global__ __launch_bounds__(128) void qkv_gemm(
    const u16* __restrict__ xbf, const u16* __restrict__ wbf,
    const float* __restrict__ bq, const float* __restrict__ bk, const float* __restrict__ bv,
    u16* __restrict__ qws, u16* __restrict__ kws, u16* __restrict__ vtws)
{
  __shared__ u16 la[2 * 64 * 32];    // 8 KB
  __shared__ u16 lb[2 * 64 * 32];    // 8 KB
  const int z     = blockIdx.z;
  const int nbase = blockIdx.x * 64;
  const int mbase = blockIdx.y * 64;
  const u16*  A    = xbf;
  const u16*  Bm   = wbf + (size_t)z * 1024 * 1024;
  const float* bias = (z == 0) ? bq : (z == 1) ? bk : bv;

  const int tid  = threadIdx.x;
  const int lane = tid & 63;
  const int wid  = tid >> 6;               // 0..1
  const int wc   = wid * 32;
  const int lr   = lane & 15, lg = lane >> 4;
  const int srow = tid >> 2;               // 0..31
  const int sc   = tid & 3;
  const int sdst = srow * 32 + sc * 8;
  const int ssrc = (sc ^ ((srow >> 1) & 3)) * 8;  // same for srow+32
  const int csw  = (lg ^ ((lr >> 1) & 3)) * 8;

  f32x4 acc[4][2];
  #pragma unroll
  for (int i = 0; i < 4; ++i) { acc[i][0] = (f32x4){0,0,0,0}; acc[i][1] = (f32x4){0,0,0,0}; }

  #define STAGEQ(u, bi) do { \
    const int k0_ = (u) * 32; \
    gload16(&A [(size_t)(mbase + srow)      * 1024 + k0_ + ssrc], &la[(bi)*2048 + sdst]); \
    gload16(&A [(size_t)(mbase + srow + 32) * 1024 + k0_ + ssrc], &la[(bi)*2048 + 1024 + sdst]); \
    gload16(&Bm[(size_t)(nbase + srow)      * 1024 + k0_ + ssrc], &lb[(bi)*2048 + sdst]); \
    gload16(&Bm[(size_t)(nbase + srow + 32) * 1024 + k0_ + ssrc], &lb[(bi)*2048 + 1024 + sdst]); \
  } while (0)

  STAGEQ(0, 0);
  __syncthreads();
  int cur = 0;
  for (int t = 0; t < 32; ++t) {
    if (t < 31) STAGEQ(t + 1, cur ^ 1);
    const int cb = cur * 2048;
    bf16x8 af[4], bfr[2];
    #pragma unroll
    for (int i = 0; i < 4; ++i)
      af[i] = *(const bf16x8*)&la[cb + (i*16 + lr)*32 + csw];
    #pragma unroll
    for (int j = 0; j < 2; ++j)
      bfr[j] = *(const bf16x8*)&lb[cb + (wc + j*16 + lr)*32 + csw];
    #pragma unroll
    for (int i = 0; i < 4; ++i)
      #pragma unroll
      for (int j = 0; j < 2; ++j)
        acc[i][j] = __builtin_amdgcn_mfma_f32_16x16x32_bf16(af[i], bfr[j], acc[i][j], 0, 0, 0);
    __syncthreads();
    cur ^= 1;
  }
  #undef STAGEQ

  #pragma unroll
  for (int i = 0; i < 4; ++i) {
    #pragma unroll
    for (int j = 0; j < 2; ++j) {
      int gn = nbase + wc + j*16 + lr;
      float bs = bias[gn];
      int h = gn >> 6, d = gn & 63;
      int gm0 = mbase + i*16 + lg*4;
      int bb = gm0 >> 11, s0 = gm0 & 2047;
      if (z == 2) {
        u16x4 vk;
        #pragma unroll
        for (int r = 0; r < 4; ++r) vk[r] = bfc(acc[i][j][r] + bs);
        *(u16x4*)&vtws[(((size_t)(bb*NHEAD + h)) * DK + d) * SEQ + s0] = vk;
      } else {
        #pragma unroll
        for (int r = 0; r < 4; ++r) {
          float v = acc[i][j][r] + bs;
          if (z == 0) qws[(((size_t)(bb*NHEAD + h)) * SEQ + s0 + r) * DK + d] = bfc(v * QSCALE);
          else        kws[(((size_t)(bb*NHEAD + h)) * SEQ + s0 + r) * DK + d] = bfc(v);
        }
      }
    }
  }
}

// ---------------- output projection: 64x64 tiles, 128-thr blocks ----------------
__global__ __launch_bounds__(128) void out_gemm(
    const u16* __restrict__ ows, const u16* __restrict__ wobf,
    const float* __restrict__ bo, float* __restrict__ out)
{
  __shared__ u16 la[2 * 64 * 32];    // 8 KB
  __shared__ u16 lb[2 * 64 * 32];    // 8 KB
  const int nbase = blockIdx.x * 64;
  const int mbase = blockIdx.y * 64;
  const int tid  = threadIdx.x;
  const int lane = tid & 63;
  const int wid  = tid >> 6;
  const int wc   = wid * 32;
  const int lr   = lane & 15, lg = lane >> 4;
  const int srow = tid >> 2;               // 0..31
  const int sc   = tid & 3;
  const int sdst = srow * 32 + sc * 8;
  const int ssrc = (sc ^ ((srow >> 1) & 3)) * 8;
  const int csw  = (lg ^ ((lr >> 1) & 3)) * 8;

  f32x4 acc[4][2];
  #pragma unroll
  for (int i = 0; i < 4; ++i) { acc[i][0] = (f32x4){0,0,0,0}; acc[i][1] = (f32x4){0,0,0,0}; }

  #define STAGEO(u, bi) do { \
    const int k0_ = (u) * 32; \
    gload16(&ows [(size_t)(mbase + srow)      * 1024 + k0_ + ssrc], &la[(bi)*2048 + sdst]); \
    gload16(&ows [(size_t)(mbase + srow + 32) * 1024 + k0_ + ssrc], &la[(bi)*2048 + 1024 + sdst]); \
    gload16(&wobf[(size_t)(nbase + srow)      * 1024 + k0_ + ssrc], &lb[(bi)*2048 + sdst]); \
    gload16(&wobf[(size_t)(nbase + srow + 32) * 1024 + k0_ + ssrc], &lb[(bi)*2048 + 1024 + sdst]); \
  } while (0)

  STAGEO(0, 0);
  __syncthreads();
  int cur = 0;
  for (int t = 0; t < 32; ++t) {
    if (t < 31) STAGEO(t + 1, cur ^ 1);
    const int cb = cur * 2048;
    bf16x8 af[4], bfr[2];
    #pragma unroll
    for (int i = 0; i < 4; ++i)
      af[i] = *(const bf16x8*)&la[cb + (i*16 + lr)*32 + csw];
    #pragma unroll
    for (int j = 0; j < 2; ++j)
      bfr[j] = *(const bf16x8*)&lb[cb + (wc + j*16 + lr)*32 + csw];
    #pragma unroll
    for (int i = 0; i < 4; ++i)
      #pragma unroll
      for (int j = 0; j < 2; ++j)
        acc[i][j] = __builtin_amdgcn_mfma_f32_16x16x32_bf16(af[i], bfr[j], acc[i][j], 0, 0, 0);
    __syncthreads();
    cur ^= 1;
  }
  #undef STAGEO

  #pragma unroll
  for (int i = 0; i < 4; ++i) {
    #pragma unroll
    for (int j = 0; j < 2; ++j) {
      int gn = nbase + wc + j*16 + lr;
      float bs = bo[gn];
      #pragma unroll
      for (int r = 0; r < 4; ++r) {
        int gm = mbase + i*16 + lg*4 + r;
        out[(size_t)gm * 1024 + gn] = acc[i][j][r] + bs;
      }
    }
  }
}

// ---------------- flash-style causal attention (1024 balanced blocks) ----------------
// Counted-vmcnt pipeline (kept from r8: non-qkv part improved under it).
__global__ __launch_bounds__(256) void attn_kernel(
    const u16* __restrict__ qws, const u16* __restrict__ kws,
    const u16* __restrict__ vtws, u16* __restrict__ ows)
{
  __shared__ u16 kbuf[2 * 64 * 64];   // 16 KB
  __shared__ u16 vbuf[2 * 64 * 64];   // 16 KB
  __shared__ u16 pbuf[4 * 16 * 64];   //  8 KB
  const int flat = blockIdx.x;                 // 0..1023
  const int r    = flat & 7;                   // XCD
  const int g    = flat >> 3;                  // 0..127 XCD-local
  const int bh_l = g >> 5;                     // 0..3
  const int qp   = g & 31;
  const int qt   = (bh_l & 1) ? qp : (31 - qp);
  const int bh   = r * 4 + bh_l;               // 0..31
  const int b = bh >> 4, h = bh & 15;
  const int tid = threadIdx.x, wid = tid >> 6, lane = tid & 63;
  const int lr = lane & 15, lg = lane >> 4;
  const u16* Q  = qws  + (size_t)(b * NHEAD + h) * SEQ * DK;
  const u16* K  = kws  + (size_t)(b * NHEAD + h) * SEQ * DK;
  const u16* Vt = vtws + (size_t)(b * NHEAD + h) * DK * SEQ;

  const int sr  = tid >> 3;                   // 0..31
  const int sc8 = (tid & 7) * 8;
  const int c0s = ((tid & 7) ^ (sr & 7)) * 8;
  const int c1s = ((tid & 7) ^ ((sr + 32) & 7)) * 8;

  #define STAGE(u, bi) do { \
    const int kb_ = (u) * 64; \
    const int off_ = (bi) * 4096; \
    gload16(&K[(size_t)(kb_ + sr) * DK + c0s],        &kbuf[off_ + sr * 64 + sc8]); \
    gload16(&K[(size_t)(kb_ + sr + 32) * DK + c1s],   &kbuf[off_ + (sr + 32) * 64 + sc8]); \
    gload16(&Vt[(size_t)sr * SEQ + kb_ + c0s],        &vbuf[off_ + sr * 64 + sc8]); \
    gload16(&Vt[(size_t)(sr + 32) * SEQ + kb_ + c1s], &vbuf[off_ + (sr + 32) * 64 + sc8]); \
  } while (0)
  #define CH(m) ((((m)*4 + lg) ^ (lr & 7)) * 8)

  const int qbase  = qt * 64 + wid * 16;
  const int q_glob = qbase + lr;

  bf16x8 qf0 = *(const bf16x8*)&Q[(size_t)q_glob * DK + lg * 8];
  bf16x8 qf1 = *(const bf16x8*)&Q[(size_t)q_glob * DK + 32 + lg * 8];

  f32x4 oacc[4];
  #pragma unroll
  for (int t = 0; t < 4; ++t) oacc[t] = (f32x4){0.f, 0.f, 0.f, 0.f};
  float l_run = 0.f;

  STAGE(0, 0);
  if (qt >= 1) STAGE(1, 1);

  for (int t = 0; t <= qt; ++t) {
    if (t < qt) asm volatile("s_waitcnt vmcnt(4)" ::: "memory");
    else        asm volatile("s_waitcnt vmcnt(0)" ::: "memory");
    BAR();

    const int diag = (t == qt);
    const int nsub = diag ? (wid + 1) : 4;   // wave-uniform
    const int cb = (t & 1) * 4096;

    // ---- S^T = K Q^T
    f32x4 sacc[4];
    __builtin_amdgcn_s_setprio(1);
    #pragma unroll
    for (int ts = 0; ts < 4; ++ts) {
      if (ts >= nsub) continue;
      bf16x8 kf0 = *(const bf16x8*)&kbuf[cb + (ts*16 + lr) * 64 + CH(0)];
      bf16x8 kf1 = *(const bf16x8*)&kbuf[cb + (ts*16 + lr) * 64 + CH(1)];
      f32x4 s0 = (f32x4){0.f, 0.f, 0.f, 0.f};
      s0 = __builtin_amdgcn_mfma_f32_16x16x32_bf16(kf0, qf0, s0, 0, 0, 0);
      s0 = __builtin_amdgcn_mfma_f32_16x16x32_bf16(kf1, qf1, s0, 0, 0, 0);
      sacc[ts] = s0;
    }
    __builtin_amdgcn_s_setprio(0);
    if (diag) {
      const int ts = wid;
      #pragma unroll
      for (int r2 = 0; r2 < 4; ++r2)
        if (lg * 4 + r2 > lr) sacc[ts][r2] = -1e30f;
    }
    // ---- fixed-shift softmax: p = exp2(s); accumulate partial l in-lane
    #pragma unroll
    for (int ts = 0; ts < 4; ++ts) {
      if (ts >= nsub) continue;
      #pragma unroll
      for (int r2 = 0; r2 < 4; ++r2) {
        float p = __builtin_amdgcn_exp2f(sacc[ts][r2]);
        sacc[ts][r2] = p;
        l_run += p;
      }
    }

    // ---- P^T -> bf16 -> LDS (swizzled), re-read as B-frags
    #pragma unroll
    for (int ts = 0; ts < 4; ++ts) {
      u16x4 pk;
      if (ts < nsub) {
        pk[0] = bfc(sacc[ts][0]); pk[1] = bfc(sacc[ts][1]);
        pk[2] = bfc(sacc[ts][2]); pk[3] = bfc(sacc[ts][3]);
      } else {
        pk[0] = 0; pk[1] = 0; pk[2] = 0; pk[3] = 0;
      }
      const int pc = (((ts*2 + (lg >> 1)) ^ (lr & 7)) * 8) + (lg & 1) * 4;
      *(u16x4*)&pbuf[wid * 1024 + lr * 64 + pc] = pk;
    }
    asm volatile("s_waitcnt lgkmcnt(0)" ::: "memory");
    __builtin_amdgcn_sched_barrier(0);
    bf16x8 pf0 = *(const bf16x8*)&pbuf[wid * 1024 + lr * 64 + CH(0)];
    bf16x8 pf1 = *(const bf16x8*)&pbuf[wid * 1024 + lr * 64 + CH(1)];

    // ---- O^T += V P
    __builtin_amdgcn_s_setprio(1);
    #pragma unroll
    for (int td = 0; td < 4; ++td) {
      bf16x8 vf0 = *(const bf16x8*)&vbuf[cb + (td*16 + lr) * 64 + CH(0)];
      bf16x8 vf1 = *(const bf16x8*)&vbuf[cb + (td*16 + lr) * 64 + CH(1)];
      oacc[td] = __builtin_amdgcn_mfma_f32_16x16x32_bf16(vf0, pf0, oacc[td], 0, 0, 0);
      oacc[td] = __builtin_amdgcn_mfma_f32_16x16x32_bf16(vf1, pf1, oacc[td], 0, 0, 0);
    }
    __builtin_amdgcn_s_setprio(0);
    BAR();
    if (t + 2 <= qt) STAGE(t + 2, t & 1);
  }

  // ---- epilogue: reduce l across the 4 lane-groups, then O / l -> ows
  float l_tot = l_run;
  l_tot += __shfl_xor(l_tot, 16);
  l_tot += __shfl_xor(l_tot, 32);
  const float inv = 1.0f / l_tot;
  #pragma unroll
  for (int td = 0; td < 4; ++td) {
    u16x4 ok;
    #pragma unroll
    for (int r2 = 0; r2 < 4; ++r2) ok[r2] = bfc(oacc[td][r2] * inv);
    *(u16x4*)&ows[((size_t)(b * SEQ + q_glob)) * D_MODEL + h * DK + td*16 + lg*4] = ok;
  }
  #undef CH
  #undef STAGE
}

// ---------------- launch ----------------
extern "C" void kernel_launch(void* const* d_in, const int* in_sizes, int n_in,
                              void* d_out, int out_size, void* d_ws, size_t ws_size,
                              hipStream_t stream) {
  const float* x  = (const float*)d_in[0];
  const float* wq = (const float*)d_in[1];
  const float* bq = (const float*)d_in[2];
  const float* wk = (const float*)d_in[3];
  const float* bk = (const float*)d_in[4];
  const float* wv = (const float*)d_in[5];
  const float* bv = (const float*)d_in[6];
  const float* wo = (const float*)d_in[7];
  const float* bo = (const float*)d_in[8];
  float* out = (float*)d_out;

  char* ws = (char*)d_ws;
  u16* qws  = (u16*)(ws + (size_t) 0 * (1 << 20));  // [b,h,s,dk]  8 MiB
  u16* kws  = (u16*)(ws + (size_t) 8 * (1 << 20));  // [b,h,s,dk]  8 MiB
  u16* vtws = (u16*)(ws + (size_t)16 * (1 << 20));  // [b,h,dk,s]  8 MiB
  u16* ows  = (u16*)(ws + (size_t)24 * (1 << 20));  // [b,s,d]     8 MiB
  u16* xbf  = (u16*)(ws + (size_t)32 * (1 << 20));  // [m,1024]    8 MiB
  u16* wbf  = (u16*)(ws + (size_t)40 * (1 << 20));  // wq|wk|wv|wo 8 MiB

  cvt_all<<<dim3(512, 5), 256, 0, stream>>>(x, wq, wk, wv, wo, xbf, wbf);

  qkv_gemm<<<dim3(16, 64, 3), 128, 0, stream>>>(
      xbf, wbf, bq, bk, bv, qws, kws, vtws);

  attn_kernel<<<dim3(1024, 1, 1), 256, 0, stream>>>(qws, kws, vtws, ows);

  out_gemm<<<dim3(16, 64), 128, 0, stream>>>(
      ows, wbf + (size_t)3 * 1024 * 1024, bo, out);
}

// Round 10
// 108.550 us; speedup vs baseline: 1.2019x; 1.2019x over previous
//
#include <hip/hip_runtime.h>

// Problem constants
#define D_MODEL 1024
#define NHEAD   16
#define DK      64
#define BATCH   2
#define SEQ     2048
#define M_TOT   (BATCH*SEQ)   // 4096

typedef unsigned short u16;
typedef unsigned int   u32;
typedef __attribute__((ext_vector_type(8))) __bf16 bf16x8;
typedef __attribute__((ext_vector_type(8))) u16   u16x8;
typedef __attribute__((ext_vector_type(4))) u16   u16x4;
typedef __attribute__((ext_vector_type(4))) float f32x4;

typedef const __attribute__((address_space(1))) u32* gas_ptr;
typedef __attribute__((address_space(3))) u32*       las_ptr;

__device__ __forceinline__ void gload16(const u16* g, u16* l) {
  __builtin_amdgcn_global_load_lds((gas_ptr)g, (las_ptr)l, 16, 0, 0);
}

__device__ __forceinline__ u16 bfc(float f) {
  union { __bf16 h; u16 u; } v; v.h = (__bf16)f; return v.u;
}

#define BAR() do { \
  __builtin_amdgcn_sched_barrier(0); \
  __builtin_amdgcn_s_barrier(); \
  __builtin_amdgcn_sched_barrier(0); \
} while (0)

// ---------------- fused fp32 -> bf16 convert (x + 4 weights, 1 launch) ----------------
__global__ void cvt_all(const float* __restrict__ x,
                        const float* __restrict__ wq, const float* __restrict__ wk,
                        const float* __restrict__ wv, const float* __restrict__ wo,
                        u16* __restrict__ xbf, u16* __restrict__ wbf) {
  const int y = blockIdx.y;
  const float* src;
  u16* dst;
  int n8;
  if (y == 0)      { src = x;  dst = xbf;                n8 = M_TOT * D_MODEL / 8; }
  else if (y == 1) { src = wq; dst = wbf;                n8 = 1024 * 1024 / 8; }
  else if (y == 2) { src = wk; dst = wbf + 1 * 1048576;  n8 = 1024 * 1024 / 8; }
  else if (y == 3) { src = wv; dst = wbf + 2 * 1048576;  n8 = 1024 * 1024 / 8; }
  else             { src = wo; dst = wbf + 3 * 1048576;  n8 = 1024 * 1024 / 8; }
  for (int i = blockIdx.x * blockDim.x + threadIdx.x; i < n8; i += gridDim.x * blockDim.x) {
    const float4* s = (const float4*)src + (size_t)i * 2;
    float4 a = s[0], b = s[1];
    u16x8 o;
    o[0]=bfc(a.x); o[1]=bfc(a.y); o[2]=bfc(a.z); o[3]=bfc(a.w);
    o[4]=bfc(b.x); o[5]=bfc(b.y); o[6]=bfc(b.z); o[7]=bfc(b.w);
    *((u16x8*)dst + i) = o;
  }
}

// Q scale: 1/sqrt(64) * log2(e)  (attention works in exp2 domain)
#define QSCALE 0.18033688011112042f

// ---------------- fused QKV projection: 128x64 tiles (r7-proven), XCD y-grouping ----------------
// 1536 blocks 1D. xcd = flat&7 owns 4 of 32 row-panels: A reuse fully L2-local
// (1 MB/XCD). Chunk swizzle (0 conflicts): chunk' = chunk ^ ((row>>1)&3).
__global__ __launch_bounds__(256) void qkv_gemm(
    const u16* __restrict__ xbf, const u16* __restrict__ wbf,
    const float* __restrict__ bq, const float* __restrict__ bk, const float* __restrict__ bv,
    u16* __restrict__ qws, u16* __restrict__ kws, u16* __restrict__ vtws)
{
  __shared__ u16 la[2 * 128 * 32];   // 16 KB
  __shared__ u16 lb[2 * 64 * 32];    //  8 KB
  const int flat = blockIdx.x;                    // 0..1535
  const int xcd  = flat & 7;
  const int loc  = flat >> 3;                     // 0..191 = 3z * 4y * 16x
  const int z    = loc >> 6;                      // 0..2
  const int rem  = loc & 63;
  const int nbase = (rem & 15) * 64;
  const int mbase = (xcd * 4 + (rem >> 4)) * 128;
  const u16*  A    = xbf;
  const u16*  Bm   = wbf + (size_t)z * 1024 * 1024;
  const float* bias = (z == 0) ? bq : (z == 1) ? bk : bv;

  const int tid  = threadIdx.x;
  const int lane = tid & 63;
  const int wid  = tid >> 6;
  const int wr   = (wid >> 1) * 64, wc = (wid & 1) * 32;
  const int lr   = lane & 15, lg = lane >> 4;
  const int srow = tid >> 2;               // 0..63
  const int sc   = tid & 3;                // chunk
  const int sdst = srow * 32 + sc * 8;     // lane-linear LDS dest
  const int ssrc = (sc ^ ((srow >> 1) & 3)) * 8;  // pre-swizzled source chunk
  const int csw  = (lg ^ ((lr >> 1) & 3)) * 8;    // swizzled read chunk (frag)

  f32x4 acc[4][2];
  #pragma unroll
  for (int i = 0; i < 4; ++i) { acc[i][0] = (f32x4){0,0,0,0}; acc[i][1] = (f32x4){0,0,0,0}; }

  {
    gload16(&A [(size_t)(mbase + srow)      * 1024 + ssrc], &la[sdst]);
    gload16(&A [(size_t)(mbase + srow + 64) * 1024 + ssrc], &la[64*32 + sdst]);
    gload16(&Bm[(size_t)(nbase + srow)      * 1024 + ssrc], &lb[sdst]);
  }
  __syncthreads();
  int cur = 0;
  for (int k0 = 0; k0 < 1024; k0 += 32) {
    if (k0 + 32 < 1024) {
      const int nb = cur ^ 1;
      gload16(&A [(size_t)(mbase + srow)      * 1024 + k0 + 32 + ssrc], &la[nb*4096 + sdst]);
      gload16(&A [(size_t)(mbase + srow + 64) * 1024 + k0 + 32 + ssrc], &la[nb*4096 + 64*32 + sdst]);
      gload16(&Bm[(size_t)(nbase + srow)      * 1024 + k0 + 32 + ssrc], &lb[nb*2048 + sdst]);
    }
    bf16x8 af[4], bfr[2];
    #pragma unroll
    for (int i = 0; i < 4; ++i)
      af[i] = *(const bf16x8*)&la[cur*4096 + (wr + i*16 + lr)*32 + csw];
    #pragma unroll
    for (int j = 0; j < 2; ++j)
      bfr[j] = *(const bf16x8*)&lb[cur*2048 + (wc + j*16 + lr)*32 + csw];
    #pragma unroll
    for (int i = 0; i < 4; ++i)
      #pragma unroll
      for (int j = 0; j < 2; ++j)
        acc[i][j] = __builtin_amdgcn_mfma_f32_16x16x32_bf16(af[i], bfr[j], acc[i][j], 0, 0, 0);
    __syncthreads();
    cur ^= 1;
  }

  #pragma unroll
  for (int i = 0; i < 4; ++i) {
    #pragma unroll
    for (int j = 0; j < 2; ++j) {
      int gn = nbase + wc + j*16 + lr;
      float bs = bias[gn];
      int h = gn >> 6, d = gn & 63;
      int gm0 = mbase + wr + i*16 + lg*4;
      int bb = gm0 >> 11, s0 = gm0 & 2047;
      if (z == 2) {
        u16x4 vk;
        #pragma unroll
        for (int r = 0; r < 4; ++r) vk[r] = bfc(acc[i][j][r] + bs);
        *(u16x4*)&vtws[(((size_t)(bb*NHEAD + h)) * DK + d) * SEQ + s0] = vk;
      } else {
        #pragma unroll
        for (int r = 0; r < 4; ++r) {
          float v = acc[i][j][r] + bs;
          if (z == 0) qws[(((size_t)(bb*NHEAD + h)) * SEQ + s0 + r) * DK + d] = bfc(v * QSCALE);
          else        kws[(((size_t)(bb*NHEAD + h)) * SEQ + s0 + r) * DK + d] = bfc(v);
        }
      }
    }
  }
}

// ---------------- output projection: 64x64 tiles, BK=64 (r7-proven), XCD y-grouping ----------------
// 1024 blocks 1D; xcd owns 8 of 64 row-panels: A(1MB)+B(2MB) fit the 4MB L2.
__global__ __launch_bounds__(256) void out_gemm(
    const u16* __restrict__ ows, const u16* __restrict__ wobf,
    const float* __restrict__ bo, float* __restrict__ out)
{
  __shared__ u16 la[2 * 64 * 64];    // 16 KB
  __shared__ u16 lb[2 * 64 * 64];    // 16 KB
  const int flat = blockIdx.x;                    // 0..1023
  const int xcd  = flat & 7;
  const int loc  = flat >> 3;                     // 0..127 = 8y * 16x
  const int nbase = (loc & 15) * 64;
  const int mbase = (xcd * 8 + (loc >> 4)) * 64;
  const int tid  = threadIdx.x;
  const int lane = tid & 63;
  const int wid  = tid >> 6;
  const int wr   = (wid >> 1) * 32, wc = (wid & 1) * 32;
  const int lr   = lane & 15, lg = lane >> 4;
  const int srow = tid >> 3;               // 0..31
  const int sc   = tid & 7;                // chunk 0..7
  const int sdst = srow * 64 + sc * 8;
  const int ssrc = (sc ^ (srow & 7)) * 8;  // (srow+32)&7 == srow&7
  const int lsw  = lr & 7;

  f32x4 acc[2][2];
  acc[0][0] = (f32x4){0,0,0,0}; acc[0][1] = (f32x4){0,0,0,0};
  acc[1][0] = (f32x4){0,0,0,0}; acc[1][1] = (f32x4){0,0,0,0};

  {
    gload16(&ows [(size_t)(mbase + srow)      * 1024 + ssrc], &la[sdst]);
    gload16(&ows [(size_t)(mbase + srow + 32) * 1024 + ssrc], &la[32*64 + sdst]);
    gload16(&wobf[(size_t)(nbase + srow)      * 1024 + ssrc], &lb[sdst]);
    gload16(&wobf[(size_t)(nbase + srow + 32) * 1024 + ssrc], &lb[32*64 + sdst]);
  }
  __syncthreads();
  int cur = 0;
  for (int k0 = 0; k0 < 1024; k0 += 64) {
    if (k0 + 64 < 1024) {
      const int nb = cur ^ 1;
      gload16(&ows [(size_t)(mbase + srow)      * 1024 + k0 + 64 + ssrc], &la[nb*4096 + sdst]);
      gload16(&ows [(size_t)(mbase + srow + 32) * 1024 + k0 + 64 + ssrc], &la[nb*4096 + 32*64 + sdst]);
      gload16(&wobf[(size_t)(nbase + srow)      * 1024 + k0 + 64 + ssrc], &lb[nb*4096 + sdst]);
      gload16(&wobf[(size_t)(nbase + srow + 32) * 1024 + k0 + 64 + ssrc], &lb[nb*4096 + 32*64 + sdst]);
    }
    bf16x8 af[2][2], bfr[2][2];
    #pragma unroll
    for (int kk = 0; kk < 2; ++kk) {
      #pragma unroll
      for (int i = 0; i < 2; ++i)
        af[i][kk] = *(const bf16x8*)&la[cur*4096 + (wr + i*16 + lr)*64 + (((kk*4 + lg) ^ lsw) * 8)];
      #pragma unroll
      for (int j = 0; j < 2; ++j)
        bfr[j][kk] = *(const bf16x8*)&lb[cur*4096 + (wc + j*16 + lr)*64 + (((kk*4 + lg) ^ lsw) * 8)];
    }
    #pragma unroll
    for (int kk = 0; kk < 2; ++kk)
      #pragma unroll
      for (int i = 0; i < 2; ++i)
        #pragma unroll
        for (int j = 0; j < 2; ++j)
          acc[i][j] = __builtin_amdgcn_mfma_f32_16x16x32_bf16(af[i][kk], bfr[j][kk], acc[i][j], 0, 0, 0);
    __syncthreads();
    cur ^= 1;
  }

  #pragma unroll
  for (int i = 0; i < 2; ++i) {
    #pragma unroll
    for (int j = 0; j < 2; ++j) {
      int gn = nbase + wc + j*16 + lr;
      float bs = bo[gn];
      #pragma unroll
      for (int r = 0; r < 4; ++r) {
        int gm = mbase + wr + i*16 + lg*4 + r;
        out[(size_t)gm * 1024 + gn] = acc[i][j][r] + bs;
      }
    }
  }
}

// ---------------- flash-style causal attention (1024 balanced blocks, r8-proven) ----------------
__global__ __launch_bounds__(256) void attn_kernel(
    const u16* __restrict__ qws, const u16* __restrict__ kws,
    const u16* __restrict__ vtws, u16* __restrict__ ows)
{
  __shared__ u16 kbuf[2 * 64 * 64];   // 16 KB
  __shared__ u16 vbuf[2 * 64 * 64];   // 16 KB
  __shared__ u16 pbuf[4 * 16 * 64];   //  8 KB
  const int flat = blockIdx.x;                 // 0..1023
  const int r    = flat & 7;                   // XCD
  const int g    = flat >> 3;                  // 0..127 XCD-local
  const int bh_l = g >> 5;                     // 0..3
  const int qp   = g & 31;
  const int qt   = (bh_l & 1) ? qp : (31 - qp);
  const int bh   = r * 4 + bh_l;               // 0..31
  const int b = bh >> 4, h = bh & 15;
  const int tid = threadIdx.x, wid = tid >> 6, lane = tid & 63;
  const int lr = lane & 15, lg = lane >> 4;
  const u16* Q  = qws  + (size_t)(b * NHEAD + h) * SEQ * DK;
  const u16* K  = kws  + (size_t)(b * NHEAD + h) * SEQ * DK;
  const u16* Vt = vtws + (size_t)(b * NHEAD + h) * DK * SEQ;

  const int sr  = tid >> 3;                   // 0..31
  const int sc8 = (tid & 7) * 8;
  const int c0s = ((tid & 7) ^ (sr & 7)) * 8;
  const int c1s = ((tid & 7) ^ ((sr + 32) & 7)) * 8;

  #define STAGE(u, bi) do { \
    const int kb_ = (u) * 64; \
    const int off_ = (bi) * 4096; \
    gload16(&K[(size_t)(kb_ + sr) * DK + c0s],        &kbuf[off_ + sr * 64 + sc8]); \
    gload16(&K[(size_t)(kb_ + sr + 32) * DK + c1s],   &kbuf[off_ + (sr + 32) * 64 + sc8]); \
    gload16(&Vt[(size_t)sr * SEQ + kb_ + c0s],        &vbuf[off_ + sr * 64 + sc8]); \
    gload16(&Vt[(size_t)(sr + 32) * SEQ + kb_ + c1s], &vbuf[off_ + (sr + 32) * 64 + sc8]); \
  } while (0)
  #define CH(m) ((((m)*4 + lg) ^ (lr & 7)) * 8)

  const int qbase  = qt * 64 + wid * 16;
  const int q_glob = qbase + lr;

  bf16x8 qf0 = *(const bf16x8*)&Q[(size_t)q_glob * DK + lg * 8];
  bf16x8 qf1 = *(const bf16x8*)&Q[(size_t)q_glob * DK + 32 + lg * 8];

  f32x4 oacc[4];
  #pragma unroll
  for (int t = 0; t < 4; ++t) oacc[t] = (f32x4){0.f, 0.f, 0.f, 0.f};
  float l_run = 0.f;

  STAGE(0, 0);
  if (qt >= 1) STAGE(1, 1);

  for (int t = 0; t <= qt; ++t) {
    if (t < qt) asm volatile("s_waitcnt vmcnt(4)" ::: "memory");
    else        asm volatile("s_waitcnt vmcnt(0)" ::: "memory");
    BAR();

    const int diag = (t == qt);
    const int nsub = diag ? (wid + 1) : 4;   // wave-uniform
    const int cb = (t & 1) * 4096;

    // ---- S^T = K Q^T
    f32x4 sacc[4];
    __builtin_amdgcn_s_setprio(1);
    #pragma unroll
    for (int ts = 0; ts < 4; ++ts) {
      if (ts >= nsub) continue;
      bf16x8 kf0 = *(const bf16x8*)&kbuf[cb + (ts*16 + lr) * 64 + CH(0)];
      bf16x8 kf1 = *(const bf16x8*)&kbuf[cb + (ts*16 + lr) * 64 + CH(1)];
      f32x4 s0 = (f32x4){0.f, 0.f, 0.f, 0.f};
      s0 = __builtin_amdgcn_mfma_f32_16x16x32_bf16(kf0, qf0, s0, 0, 0, 0);
      s0 = __builtin_amdgcn_mfma_f32_16x16x32_bf16(kf1, qf1, s0, 0, 0, 0);
      sacc[ts] = s0;
    }
    __builtin_amdgcn_s_setprio(0);
    if (diag) {
      const int ts = wid;
      #pragma unroll
      for (int r2 = 0; r2 < 4; ++r2)
        if (lg * 4 + r2 > lr) sacc[ts][r2] = -1e30f;
    }
    // ---- fixed-shift softmax: p = exp2(s); accumulate partial l in-lane
    #pragma unroll
    for (int ts = 0; ts < 4; ++ts) {
      if (ts >= nsub) continue;
      #pragma unroll
      for (int r2 = 0; r2 < 4; ++r2) {
        float p = __builtin_amdgcn_exp2f(sacc[ts][r2]);
        sacc[ts][r2] = p;
        l_run += p;
      }
    }

    // ---- P^T -> bf16 -> LDS (swizzled), re-read as B-frags
    #pragma unroll
    for (int ts = 0; ts < 4; ++ts) {
      u16x4 pk;
      if (ts < nsub) {
        pk[0] = bfc(sacc[ts][0]); pk[1] = bfc(sacc[ts][1]);
        pk[2] = bfc(sacc[ts][2]); pk[3] = bfc(sacc[ts][3]);
      } else {
        pk[0] = 0; pk[1] = 0; pk[2] = 0; pk[3] = 0;
      }
      const int pc = (((ts*2 + (lg >> 1)) ^ (lr & 7)) * 8) + (lg & 1) * 4;
      *(u16x4*)&pbuf[wid * 1024 + lr * 64 + pc] = pk;
    }
    asm volatile("s_waitcnt lgkmcnt(0)" ::: "memory");
    __builtin_amdgcn_sched_barrier(0);
    bf16x8 pf0 = *(const bf16x8*)&pbuf[wid * 1024 + lr * 64 + CH(0)];
    bf16x8 pf1 = *(const bf16x8*)&pbuf[wid * 1024 + lr * 64 + CH(1)];

    // ---- O^T += V P
    __builtin_amdgcn_s_setprio(1);
    #pragma unroll
    for (int td = 0; td < 4; ++td) {
      bf16x8 vf0 = *(const bf16x8*)&vbuf[cb + (td*16 + lr) * 64 + CH(0)];
      bf16x8 vf1 = *(const bf16x8*)&vbuf[cb + (td*16 + lr) * 64 + CH(1)];
      oacc[td] = __builtin_amdgcn_mfma_f32_16x16x32_bf16(vf0, pf0, oacc[td], 0, 0, 0);
      oacc[td] = __builtin_amdgcn_mfma_f32_16x16x32_bf16(vf1, pf1, oacc[td], 0, 0, 0);
    }
    __builtin_amdgcn_s_setprio(0);
    BAR();
    if (t + 2 <= qt) STAGE(t + 2, t & 1);
  }

  // ---- epilogue: reduce l across the 4 lane-groups, then O / l -> ows
  float l_tot = l_run;
  l_tot += __shfl_xor(l_tot, 16);
  l_tot += __shfl_xor(l_tot, 32);
  const float inv = 1.0f / l_tot;
  #pragma unroll
  for (int td = 0; td < 4; ++td) {
    u16x4 ok;
    #pragma unroll
    for (int r2 = 0; r2 < 4; ++r2) ok[r2] = bfc(oacc[td][r2] * inv);
    *(u16x4*)&ows[((size_t)(b * SEQ + q_glob)) * D_MODEL + h * DK + td*16 + lg*4] = ok;
  }
  #undef CH
  #undef STAGE
}

// ---------------- launch ----------------
extern "C" void kernel_launch(void* const* d_in, const int* in_sizes, int n_in,
                              void* d_out, int out_size, void* d_ws, size_t ws_size,
                              hipStream_t stream) {
  const float* x  = (const float*)d_in[0];
  const float* wq = (const float*)d_in[1];
  const float* bq = (const float*)d_in[2];
  const float* wk = (const float*)d_in[3];
  const float* bk = (const float*)d_in[4];
  const float* wv = (const float*)d_in[5];
  const float* bv = (const float*)d_in[6];
  const float* wo = (const float*)d_in[7];
  const float* bo = (const float*)d_in[8];
  float* out = (float*)d_out;

  char* ws = (char*)d_ws;
  u16* qws  = (u16*)(ws + (size_t) 0 * (1 << 20));  // [b,h,s,dk]  8 MiB
  u16* kws  = (u16*)(ws + (size_t) 8 * (1 << 20));  // [b,h,s,dk]  8 MiB
  u16* vtws = (u16*)(ws + (size_t)16 * (1 << 20));  // [b,h,dk,s]  8 MiB
  u16* ows  = (u16*)(ws + (size_t)24 * (1 << 20));  // [b,s,d]     8 MiB
  u16* xbf  = (u16*)(ws + (size_t)32 * (1 << 20));  // [m,1024]    8 MiB
  u16* wbf  = (u16*)(ws + (size_t)40 * (1 << 20));  // wq|wk|wv|wo 8 MiB

  cvt_all<<<dim3(512, 5), 256, 0, stream>>>(x, wq, wk, wv, wo, xbf, wbf);

  qkv_gemm<<<dim3(1536, 1, 1), 256, 0, stream>>>(
      xbf, wbf, bq, bk, bv, qws, kws, vtws);

  attn_kernel<<<dim3(1024, 1, 1), 256, 0, stream>>>(qws, kws, vtws, ows);

  out_gemm<<<dim3(1024, 1, 1), 256, 0, stream>>>(
      ows, wbf + (size_t)3 * 1024 * 1024, bo, out);
}